// Round 1
// baseline (226.270 us; speedup 1.0000x reference)
//
#include <hip/hip_runtime.h>
#include <math.h>

#define Mv 8
#define Nv 8192
#define Kv 256
#define BPM 128           // blocks per m -> 1024 blocks per iteration kernel (4/CU)
#define NBLK (Mv*BPM)
#define WSTRIDE (4*BPM)   // wave-slots per m (waves striding the n loop)
#define NITER 6
#define EPSILON_C 0.01f
#define GAMMA_C 0.005f

// ws layout (float offsets)
#define WS_R     0        // 72   (M x 3 x 3) -- initial identity (p0)
#define WS_T     72       // 24   (M x 3)     -- initial t0 (p0)
#define WS_X     96       // 768  (K x 3)     -- X0 (p0; never overwritten)
#define WS_Q     864      // 256  -- Q0
#define WS_BETA  1120     // 1
#define WS_ACC   1124     // 3 x ACCSZ triple-buffered accumulators
#define AC_STATS 0        // 128 (M x 16)
#define AC_L     128      // 2048 (M x K)
#define AC_W     2176     // 6144 (M x 3 x K)
#define AC_H     8320     // 2048 (M x K)
#define ACCSZ    10368

// ---- wave-wide sum via DPP; wave-uniform result. All lanes must be active.
__device__ __forceinline__ float wave_red_sum(float x) {
  int v;
  float t;
  v = __builtin_bit_cast(int, x);
  t = __builtin_bit_cast(float, __builtin_amdgcn_update_dpp(0, v, 0x111, 0xf, 0xf, true));  // row_shr:1
  x += t; v = __builtin_bit_cast(int, x);
  t = __builtin_bit_cast(float, __builtin_amdgcn_update_dpp(0, v, 0x112, 0xf, 0xf, true));  // row_shr:2
  x += t; v = __builtin_bit_cast(int, x);
  t = __builtin_bit_cast(float, __builtin_amdgcn_update_dpp(0, v, 0x114, 0xf, 0xf, true));  // row_shr:4
  x += t; v = __builtin_bit_cast(int, x);
  t = __builtin_bit_cast(float, __builtin_amdgcn_update_dpp(0, v, 0x118, 0xf, 0xf, true));  // row_shr:8
  x += t; v = __builtin_bit_cast(int, x);
  t = __builtin_bit_cast(float, __builtin_amdgcn_update_dpp(0, v, 0x142, 0xa, 0xf, false)); // row_bcast:15
  x += t; v = __builtin_bit_cast(int, x);
  t = __builtin_bit_cast(float, __builtin_amdgcn_update_dpp(0, v, 0x143, 0xc, 0xf, false)); // row_bcast:31
  x += t;
  return __builtin_bit_cast(float, __builtin_amdgcn_readlane(__builtin_bit_cast(int, x), 63));
}

// ---------------------------------------------------------------- init
__global__ __launch_bounds__(256) void p0_init(const float* __restrict__ Vs,
                                               const float* __restrict__ X0,
                                               const float* __restrict__ Q0,
                                               float* __restrict__ ws) {
  __shared__ float sred[4];
  int tid = threadIdx.x;
  int b = blockIdx.x;
  int wave = tid >> 6, lane = tid & 63;
  if (b < 24) {
    int m = b / 3, d = b % 3;
    const float* src = Vs + (size_t)(m*3 + d) * Nv;
    float s = 0.f;
    for (int n = tid; n < Nv; n += 256) s += src[n];
    s = wave_red_sum(s);
    if (lane == 0) sred[wave] = s;
    __syncthreads();
    if (tid == 0) {
      float tot = sred[0]+sred[1]+sred[2]+sred[3];
      ws[WS_T + m*3 + d] = -tot / (float)Nv;
    }
    if (d == 0 && tid < 9) {
      ws[WS_R + m*9 + tid] = (tid==0||tid==4||tid==8) ? 1.f : 0.f;
    }
  } else {
    float s = (tid < Kv) ? Q0[tid] : 0.f;
    s = wave_red_sum(s);
    if (lane == 0) sred[wave] = s;
    __syncthreads();
    if (tid == 0) {
      float mq = (sred[0]+sred[1]+sred[2]+sred[3]) / (float)Kv;
      ws[WS_BETA] = GAMMA_C * mq * sqrtf(mq);
    }
    if (tid < Kv) ws[WS_Q + tid] = Q0[tid];
    for (int i = tid; i < Kv*3; i += 256) ws[WS_X + i] = X0[i];
    for (int i = tid; i < ACCSZ; i += 256) ws[WS_ACC + i] = 0.f;
  }
}

// ---- fp32 Jacobi rotation, COMPILE-TIME pair, named scalars only.
#define JROTF(app,aqq,apq,apr,aqr, vp0,vp1,vp2, vq0,vq1,vq2) do {           \
    float tau_ = (aqq - app) * __builtin_amdgcn_rcpf(2.0f*apq);             \
    float tt_ = __builtin_amdgcn_rcpf(fabsf(tau_) +                         \
                   __builtin_amdgcn_sqrtf(fmaf(tau_,tau_,1.0f)));           \
    tt_ = (tau_ < 0.0f) ? -tt_ : tt_;                                       \
    tt_ = (apq == 0.0f) ? 0.0f : tt_;                                       \
    float c_ = __builtin_amdgcn_rsqf(fmaf(tt_,tt_,1.0f)), s_ = tt_*c_;      \
    float papq_ = apq;                                                      \
    app = fmaf(-tt_,papq_,app); aqq = fmaf(tt_,papq_,aqq); apq = 0.0f;      \
    float tp_ = apr, tq_ = aqr;                                             \
    apr = c_*tp_ - s_*tq_; aqr = s_*tp_ + c_*tq_;                           \
    tp_=vp0; tq_=vq0; vp0=c_*tp_-s_*tq_; vq0=s_*tp_+c_*tq_;                 \
    tp_=vp1; tq_=vq1; vp1=c_*tp_-s_*tq_; vq1=s_*tp_+c_*tq_;                 \
    tp_=vp2; tq_=vq2; vp2=c_*tp_-s_*tq_; vq2=s_*tp_+c_*tq_;                 \
  } while(0)

#define CSWAP3F(la,lb, a0,a1,a2, b0,b1,b2) do {                             \
    if (la < lb) { float t_;                                                \
      t_=la; la=lb; lb=t_; t_=a0; a0=b0; b0=t_;                             \
      t_=a1; a1=b1; b1=t_; t_=a2; a2=b2; b2=t_; }                           \
  } while(0)

// ---- redundant small update for iteration `itprev` from acc -> sX/sQ/sR/sT.
// Runs identically in every block. Contains one internal __syncthreads;
// caller must __syncthreads() after before reading other threads' sX/sQ.
template<int ITPREV>
__device__ __forceinline__ void small_update(const float* __restrict__ acc,
                                             const float* __restrict__ ws,
                                             int tid,
                                             float (*sX)[3], float* sQ,
                                             float (*sR)[9], float (*sT)[3],
                                             float* sTn) {
  const int k = tid;
  float lk[Mv], w0v[Mv], w1v[Mv], w2v[Mv], hk[Mv];
  #pragma unroll
  for (int mm=0;mm<Mv;mm++) {
    lk[mm]  = acc[AC_L + mm*Kv + k];
    w0v[mm] = acc[AC_W + (mm*3+0)*Kv + k];
    w1v[mm] = acc[AC_W + (mm*3+1)*Kv + k];
    w2v[mm] = acc[AC_W + (mm*3+2)*Kv + k];
    hk[mm]  = acc[AC_H + mm*Kv + k];
  }
  float xp0 = 0.f, xp1 = 0.f, xp2 = 0.f;
  if (ITPREV <= 1) {
    xp0 = ws[WS_X + k*3+0]; xp1 = ws[WS_X + k*3+1]; xp2 = ws[WS_X + k*3+2];
  }

  if (tid < Mv) {
    int mm = tid;
    const float* st = acc + AC_STATS + mm*16;
    float s0=st[0], s1=st[1], s2v=st[2], s3=st[3], s4=st[4], s5=st[5],
          s6=st[6], s7=st[7], s8=st[8], s9=st[9], s10=st[10], s11=st[11],
          s12=st[12], s13=st[13], s14=st[14], s15=st[15];
    float z = s0;
    float mX0 = s1, mX1 = s2v, mX2 = s3;
    float mW0 = s4, mW1 = s5, mW2 = s6;
    float iz = __builtin_amdgcn_rcpf(z);
    float P00 = s7  - mX0*mW0*iz;
    float P01 = s8  - mX0*mW1*iz;
    float P02 = s9  - mX0*mW2*iz;
    float P10 = s10 - mX1*mW0*iz;
    float P11 = s11 - mX1*mW1*iz;
    float P12 = s12 - mX1*mW2*iz;
    float P20 = s13 - mX2*mW0*iz;
    float P21 = s14 - mX2*mW1*iz;
    float P22 = s15 - mX2*mW2*iz;
    float a00 = P00*P00 + P10*P10 + P20*P20;
    float a01 = P00*P01 + P10*P11 + P20*P21;
    float a02 = P00*P02 + P10*P12 + P20*P22;
    float a11 = P01*P01 + P11*P11 + P21*P21;
    float a12 = P01*P02 + P11*P12 + P21*P22;
    float a22 = P02*P02 + P12*P12 + P22*P22;
    float v00=1, v01=0, v02=0, v10=0, v11=1, v12=0, v20=0, v21=0, v22=1;
    #pragma unroll 1
    for (int sweep = 0; sweep < 8; sweep++) {
      JROTF(a00,a11,a01, a02,a12, v00,v10,v20, v01,v11,v21);
      JROTF(a00,a22,a02, a01,a12, v00,v10,v20, v02,v12,v22);
      JROTF(a11,a22,a12, a01,a02, v01,v11,v21, v02,v12,v22);
    }
    float l0 = a00, l1 = a11, l2 = a22;
    CSWAP3F(l0,l1, v00,v10,v20, v01,v11,v21);
    CSWAP3F(l1,l2, v01,v11,v21, v02,v12,v22);
    CSWAP3F(l0,l1, v00,v10,v20, v01,v11,v21);
    float detP = P00*(P11*P22-P12*P21) - P01*(P10*P22-P12*P20)
               + P02*(P10*P21-P11*P20);
    float s2d = (detP < 0.0f) ? -1.0f : 1.0f;
    float tiny = 1e-18f*l0 + 1e-30f;
    float w0i = __builtin_amdgcn_rsqf(fmaxf(l0,tiny));
    float w1i = __builtin_amdgcn_rsqf(fmaxf(l1,tiny));
    float w2i = s2d*__builtin_amdgcn_rsqf(fmaxf(l2,tiny));
    float M00 = w0i*v00*v00 + w1i*v01*v01 + w2i*v02*v02;
    float M01 = w0i*v00*v10 + w1i*v01*v11 + w2i*v02*v12;
    float M02 = w0i*v00*v20 + w1i*v01*v21 + w2i*v02*v22;
    float M11 = w0i*v10*v10 + w1i*v11*v11 + w2i*v12*v12;
    float M12 = w0i*v10*v20 + w1i*v11*v21 + w2i*v12*v22;
    float M22 = w0i*v20*v20 + w1i*v21*v21 + w2i*v22*v22;
    float R00n = P00*M00 + P01*M01 + P02*M02;
    float R01n = P00*M01 + P01*M11 + P02*M12;
    float R02n = P00*M02 + P01*M12 + P02*M22;
    float R10n = P10*M00 + P11*M01 + P12*M02;
    float R11n = P10*M01 + P11*M11 + P12*M12;
    float R12n = P10*M02 + P11*M12 + P12*M22;
    float R20n = P20*M00 + P21*M01 + P22*M02;
    float R21n = P20*M01 + P21*M11 + P22*M12;
    float R22n = P20*M02 + P21*M12 + P22*M22;
    float tm0 = (mX0 - (R00n*mW0 + R01n*mW1 + R02n*mW2))*iz;
    float tm1 = (mX1 - (R10n*mW0 + R11n*mW1 + R12n*mW2))*iz;
    float tm2 = (mX2 - (R20n*mW0 + R21n*mW1 + R22n*mW2))*iz;
    sR[mm][0]=R00n; sR[mm][1]=R01n; sR[mm][2]=R02n;
    sR[mm][3]=R10n; sR[mm][4]=R11n; sR[mm][5]=R12n;
    sR[mm][6]=R20n; sR[mm][7]=R21n; sR[mm][8]=R22n;
    sT[mm][0]=tm0; sT[mm][1]=tm1; sT[mm][2]=tm2;
    sTn[mm] = tm0*tm0 + tm1*tm1 + tm2*tm2;
  }
  __syncthreads();
  {
    float den = 0.f, Xn0=0.f, Xn1=0.f, Xn2=0.f, S2=0.f;
    #pragma unroll
    for (int mm=0;mm<Mv;mm++) {
      float r0 = sR[mm][0]*w0v[mm] + sR[mm][1]*w1v[mm] + sR[mm][2]*w2v[mm];
      float r1 = sR[mm][3]*w0v[mm] + sR[mm][4]*w1v[mm] + sR[mm][5]*w2v[mm];
      float r2 = sR[mm][6]*w0v[mm] + sR[mm][7]*w1v[mm] + sR[mm][8]*w2v[mm];
      float tt0 = sT[mm][0], tt1 = sT[mm][1], tt2 = sT[mm][2];
      den += lk[mm];
      Xn0 += r0 + tt0*lk[mm]; Xn1 += r1 + tt1*lk[mm]; Xn2 += r2 + tt2*lk[mm];
      S2  += hk[mm] + 2.f*(tt0*r0+tt1*r1+tt2*r2) + sTn[mm]*lk[mm];
    }
    float x0, x1, x2;
    if (ITPREV > 1) { float inv = __builtin_amdgcn_rcpf(den);
                      x0=Xn0*inv; x1=Xn1*inv; x2=Xn2*inv; }
    else            { x0=xp0; x1=xp1; x2=xp2; }
    float wn = S2 + (x0*x0+x1*x1+x2*x2)*den - 2.f*(x0*Xn0+x1*Xn1+x2*Xn2);
    float qn = 3.f*den / (wn + 3.f*den*EPSILON_C);
    sX[k][0]=x0; sX[k][1]=x1; sX[k][2]=x2;
    sQ[k] = qn;
  }
}

// ------------------------------------------- one-iteration kernel (1024 blocks)
// Templated on IT so (a) rocprof reports each iteration as a distinct kernel,
// (b) branches fold. launch_bounds(256,4): 4 waves/SIMD -> VGPR capped at 128
// so the grid's 4 blocks/CU actually become resident.
template<int IT>
__global__ __launch_bounds__(256, 4) void p_iter(const float* __restrict__ Vs,
                                                 float* __restrict__ ws) {
  __shared__ float sb[4][5][Kv]; // 20 KB
  __shared__ float st4[4][16];
  __shared__ float sX[Kv][3];
  __shared__ float sQ[Kv];
  __shared__ float sR[Mv][9];
  __shared__ float sT[Mv][3];
  __shared__ float sTn[Mv];

  int tid  = threadIdx.x;
  int wave = tid >> 6, lane = tid & 63;
  int bid  = blockIdx.x;
  int m    = bid / BPM;
  int blk  = bid % BPM;
  // readfirstlane: force wave-uniform so V0[n]/V1[n]/V2[n] become s_load
  int wid  = __builtin_amdgcn_readfirstlane(blk*4 + wave);
  const int k = tid;

  float* acc  = ws + WS_ACC + (IT % 3)*ACCSZ;
  float* accz = ws + WS_ACC + ((IT+1) % 3)*ACCSZ;
  float beta = ws[WS_BETA];

  if (IT == 0) {
    if (tid < 72) ((float*)sR)[tid] = ws[WS_R + tid];
    if (tid < 24) ((float*)sT)[tid] = ws[WS_T + tid];
    sX[k][0] = ws[WS_X + 3*k+0];
    sX[k][1] = ws[WS_X + 3*k+1];
    sX[k][2] = ws[WS_X + 3*k+2];
    sQ[k]    = ws[WS_Q + k];
  } else {
    const float* accp = ws + WS_ACC + ((IT+2) % 3)*ACCSZ;  // (IT-1)%3
    small_update<(IT > 0) ? (IT-1) : 0>(accp, ws, tid, sX, sQ, sR, sT, sTn);
  }
  __syncthreads();

  // partitioned zero of buffer (IT+1)%3 (11*1024 >= ACCSZ)
  { int base = bid*11;
    if (tid < 11 && base + tid < ACCSZ) accz[base + tid] = 0.f; }

  // ---- phase A
  float R00=sR[m][0],R01=sR[m][1],R02=sR[m][2];
  float R10=sR[m][3],R11=sR[m][4],R12=sR[m][5];
  float R20=sR[m][6],R21=sR[m][7],R22=sR[m][8];
  float t0=sT[m][0], t1=sT[m][1], t2=sT[m][2];
  const float L2E = 1.4426950408889634f;   // log2(e): fold into exp coeffs
  float kXx[4],kXy[4],kXz[4],kA[4],kB[4],kQ32[4];
  #pragma unroll
  for (int j=0;j<4;j++) {
    int kk = lane + 64*j;
    float xx = sX[kk][0], xy = sX[kk][1], xz = sX[kk][2];
    float q  = sQ[kk];
    float qL = q * L2E;
    kA[j]  = -0.5f*qL;
    kXx[j] = qL*xx; kXy[j] = qL*xy; kXz[j] = qL*xz;  // q*log2e folded into X
    kB[j]  = kA[j]*(xx*xx+xy*xy+xz*xz);
    kQ32[j]= q*sqrtf(q);
  }
  float aL[4]={0,0,0,0}, aWx[4]={0,0,0,0}, aWy[4]={0,0,0,0},
        aWz[4]={0,0,0,0}, aH[4]={0,0,0,0};
  const float* V0 = Vs + (size_t)(m*3+0)*Nv;
  const float* V1 = Vs + (size_t)(m*3+1)*Nv;
  const float* V2 = Vs + (size_t)(m*3+2)*Nv;
  // 2-deep manual unroll: two independent exp->reduce chains per iteration
  #pragma unroll 1
  for (int i = 0; i < Nv/(2*WSTRIDE); i++) {
    int n0 = wid + (2*WSTRIDE)*i;
    int n1 = n0 + WSTRIDE;
    float vx0 = V0[n0], vy0 = V1[n0], vz0 = V2[n0];
    float vx1 = V0[n1], vy1 = V1[n1], vz1 = V2[n1];
    float px0 = fmaf(R00,vx0, fmaf(R01,vy0, fmaf(R02,vz0, t0)));
    float py0 = fmaf(R10,vx0, fmaf(R11,vy0, fmaf(R12,vz0, t1)));
    float pz0 = fmaf(R20,vx0, fmaf(R21,vy0, fmaf(R22,vz0, t2)));
    float px1 = fmaf(R00,vx1, fmaf(R01,vy1, fmaf(R02,vz1, t0)));
    float py1 = fmaf(R10,vx1, fmaf(R11,vy1, fmaf(R12,vz1, t1)));
    float pz1 = fmaf(R20,vx1, fmaf(R21,vy1, fmaf(R22,vz1, t2)));
    float tvn0 = fmaf(px0,px0, fmaf(py0,py0, pz0*pz0));
    float tvn1 = fmaf(px1,px1, fmaf(py1,py1, pz1*pz1));
    float vn0  = fmaf(vx0,vx0, fmaf(vy0,vy0, vz0*vz0));
    float vn1  = fmaf(vx1,vx1, fmaf(vy1,vy1, vz1*vz1));
    float ap0[4], ap1[4];
    float s0 = 0.f, s1 = 0.f;
    #pragma unroll
    for (int j=0;j<4;j++) {
      float b0 = fmaf(kA[j], tvn0, kB[j]);
      float b1 = fmaf(kA[j], tvn1, kB[j]);
      float arg0 = fmaf(px0,kXx[j], fmaf(py0,kXy[j], fmaf(pz0,kXz[j], b0)));
      float arg1 = fmaf(px1,kXx[j], fmaf(py1,kXy[j], fmaf(pz1,kXz[j], b1)));
      float e0 = __builtin_amdgcn_exp2f(arg0) * kQ32[j];
      float e1 = __builtin_amdgcn_exp2f(arg1) * kQ32[j];
      ap0[j] = e0; s0 += e0;
      ap1[j] = e1; s1 += e1;
    }
    float S0 = wave_red_sum(s0);
    float S1 = wave_red_sum(s1);
    float inv0 = __builtin_amdgcn_rcpf(S0 + beta);
    float inv1 = __builtin_amdgcn_rcpf(S1 + beta);
    #pragma unroll
    for (int j=0;j<4;j++) {
      float a0 = ap0[j]*inv0;
      float a1 = ap1[j]*inv1;
      aL[j] += a0 + a1;
      aWx[j] = fmaf(a1,vx1, fmaf(a0,vx0, aWx[j]));
      aWy[j] = fmaf(a1,vy1, fmaf(a0,vy0, aWy[j]));
      aWz[j] = fmaf(a1,vz1, fmaf(a0,vz0, aWz[j]));
      aH[j]  = fmaf(a1,vn1, fmaf(a0,vn0, aH[j]));
    }
  }
  #pragma unroll
  for (int j=0;j<4;j++) {
    int kk = lane + 64*j;
    sb[wave][0][kk]=aL[j];  sb[wave][1][kk]=aWx[j]; sb[wave][2][kk]=aWy[j];
    sb[wave][3][kk]=aWz[j]; sb[wave][4][kk]=aH[j];
  }
  __syncthreads();
  // block-permuted column: breaks cross-block same-address atomic pile-up
  const int k2 = (tid + 4*blk) & (Kv-1);
  float vL  = sb[0][0][k2]+sb[1][0][k2]+sb[2][0][k2]+sb[3][0][k2];
  float vWx = sb[0][1][k2]+sb[1][1][k2]+sb[2][1][k2]+sb[3][1][k2];
  float vWy = sb[0][2][k2]+sb[1][2][k2]+sb[2][2][k2]+sb[3][2][k2];
  float vWz = sb[0][3][k2]+sb[1][3][k2]+sb[2][3][k2]+sb[3][3][k2];
  float vH  = sb[0][4][k2]+sb[1][4][k2]+sb[2][4][k2]+sb[3][4][k2];
  atomicAdd(&acc[AC_L + m*Kv + k2], vL);
  atomicAdd(&acc[AC_W + (m*3+0)*Kv + k2], vWx);
  atomicAdd(&acc[AC_W + (m*3+1)*Kv + k2], vWy);
  atomicAdd(&acc[AC_W + (m*3+2)*Kv + k2], vWz);
  atomicAdd(&acc[AC_H + m*Kv + k2], vH);
  {
    float q  = sQ[k2];
    float x0 = sX[k2][0], x1 = sX[k2][1], x2 = sX[k2][2];
    float bk = vL*q;
    float sw0 = vWx*q, sw1 = vWy*q, sw2 = vWz*q;
    float pr[16];
    pr[0]=bk;  pr[1]=bk*x0; pr[2]=bk*x1; pr[3]=bk*x2;
    pr[4]=sw0; pr[5]=sw1;   pr[6]=sw2;
    pr[7]=sw0*x0;  pr[8]=sw1*x0;  pr[9]=sw2*x0;
    pr[10]=sw0*x1; pr[11]=sw1*x1; pr[12]=sw2*x1;
    pr[13]=sw0*x2; pr[14]=sw1*x2; pr[15]=sw2*x2;
    float red[16];
    #pragma unroll
    for (int v2=0; v2<16; v2++) red[v2] = wave_red_sum(pr[v2]);
    if (lane == 0) {
      #pragma unroll
      for (int v2=0; v2<16; v2++) st4[wave][v2] = red[v2];
    }
    __syncthreads();
    if (tid < 16)
      atomicAdd(&acc[AC_STATS + m*16 + ((tid + blk) & 15)],
                st4[0][(tid+blk)&15]+st4[1][(tid+blk)&15]+
                st4[2][(tid+blk)&15]+st4[3][(tid+blk)&15]);
  }
}

// ------------------------------- final: prologue finalizes iter 5, then write
#define OUT_TOTAL (Mv*3*Nv + 72 + 24 + Kv*3)
__global__ __launch_bounds__(256) void p3_final(const float* __restrict__ Vs,
                                                const float* __restrict__ ws,
                                                float* __restrict__ out) {
  __shared__ float sX[Kv][3];
  __shared__ float sQ[Kv];
  __shared__ float sR[Mv][9];
  __shared__ float sT[Mv][3];
  __shared__ float sTn[Mv];
  int tid = threadIdx.x;
  const float* acc = ws + WS_ACC + ((NITER-1) % 3)*ACCSZ;
  small_update<NITER-1>(acc, ws, tid, sX, sQ, sR, sT, sTn);
  __syncthreads();

  for (int idx = blockIdx.x*256 + tid; idx < OUT_TOTAL; idx += 256*256) {
    if (idx < Mv*3*Nv) {
      int m = idx / (3*Nv);
      int r = idx % (3*Nv);
      int d = r / Nv;
      int n = r % Nv;
      float vx = Vs[(size_t)(m*3+0)*Nv + n];
      float vy = Vs[(size_t)(m*3+1)*Nv + n];
      float vz = Vs[(size_t)(m*3+2)*Nv + n];
      out[idx] = fmaf(sR[m][d*3+0],vx,
                 fmaf(sR[m][d*3+1],vy,
                 fmaf(sR[m][d*3+2],vz, sT[m][d])));
    } else {
      int j = idx - Mv*3*Nv;
      float v;
      if (j < 72)      v = ((float*)sR)[j];
      else if (j < 96) v = ((float*)sT)[j-72];
      else             v = ((float*)sX)[j-96];
      out[idx] = v;
    }
  }
}

extern "C" void kernel_launch(void* const* d_in, const int* in_sizes, int n_in,
                              void* d_out, int out_size, void* d_ws, size_t ws_size,
                              hipStream_t stream) {
  const float* Vs = (const float*)d_in[0];
  const float* X0 = (const float*)d_in[1];
  const float* Q0 = (const float*)d_in[2];
  float* out = (float*)d_out;
  float* ws  = (float*)d_ws;

  p0_init<<<25, 256, 0, stream>>>(Vs, X0, Q0, ws);
  p_iter<0><<<NBLK, 256, 0, stream>>>(Vs, ws);
  p_iter<1><<<NBLK, 256, 0, stream>>>(Vs, ws);
  p_iter<2><<<NBLK, 256, 0, stream>>>(Vs, ws);
  p_iter<3><<<NBLK, 256, 0, stream>>>(Vs, ws);
  p_iter<4><<<NBLK, 256, 0, stream>>>(Vs, ws);
  p_iter<5><<<NBLK, 256, 0, stream>>>(Vs, ws);
  p3_final<<<256, 256, 0, stream>>>(Vs, ws, out);
}

// Round 2
// 207.684 us; speedup vs baseline: 1.0895x; 1.0895x over previous
//
#include <hip/hip_runtime.h>
#include <math.h>

#define Mv 8
#define Nv 8192
#define Kv 256
#define BPM 32            // blocks per m -> 256 blocks total, 1 per CU
#define NBLK (Mv*BPM)
#define NPB (Nv/BPM)      // 256 points per block (one per thread)
#define NITER 6
#define EPSILON_C 0.01f
#define GAMMA_C 0.005f

// ws layout (float offsets)
#define WS_R     0        // 72   (M x 3 x 3) -- initial identity (p0)
#define WS_T     72       // 24   (M x 3)     -- initial t0 (p0)
#define WS_X     96       // 768  (K x 3)     -- X0 (p0; never overwritten)
#define WS_Q     864      // 256  -- Q0
#define WS_BETA  1120     // 1
#define WS_ACC   1124     // 3 x ACCSZ triple-buffered accumulators
#define AC_STATS 0        // 128 (M x 16)
#define AC_L     128      // 2048 (M x K)
#define AC_W     2176     // 6144 (M x 3 x K)
#define AC_H     8320     // 2048 (M x K)
#define ACCSZ    10368

// ---- wave-wide sum via DPP; wave-uniform result. All lanes must be active.
__device__ __forceinline__ float wave_red_sum(float x) {
  int v;
  float t;
  v = __builtin_bit_cast(int, x);
  t = __builtin_bit_cast(float, __builtin_amdgcn_update_dpp(0, v, 0x111, 0xf, 0xf, true));  // row_shr:1
  x += t; v = __builtin_bit_cast(int, x);
  t = __builtin_bit_cast(float, __builtin_amdgcn_update_dpp(0, v, 0x112, 0xf, 0xf, true));  // row_shr:2
  x += t; v = __builtin_bit_cast(int, x);
  t = __builtin_bit_cast(float, __builtin_amdgcn_update_dpp(0, v, 0x114, 0xf, 0xf, true));  // row_shr:4
  x += t; v = __builtin_bit_cast(int, x);
  t = __builtin_bit_cast(float, __builtin_amdgcn_update_dpp(0, v, 0x118, 0xf, 0xf, true));  // row_shr:8
  x += t; v = __builtin_bit_cast(int, x);
  t = __builtin_bit_cast(float, __builtin_amdgcn_update_dpp(0, v, 0x142, 0xa, 0xf, false)); // row_bcast:15
  x += t; v = __builtin_bit_cast(int, x);
  t = __builtin_bit_cast(float, __builtin_amdgcn_update_dpp(0, v, 0x143, 0xc, 0xf, false)); // row_bcast:31
  x += t;
  return __builtin_bit_cast(float, __builtin_amdgcn_readlane(__builtin_bit_cast(int, x), 63));
}

// ---------------------------------------------------------------- init
__global__ __launch_bounds__(256) void p0_init(const float* __restrict__ Vs,
                                               const float* __restrict__ X0,
                                               const float* __restrict__ Q0,
                                               float* __restrict__ ws) {
  __shared__ float sred[4];
  int tid = threadIdx.x;
  int b = blockIdx.x;
  int wave = tid >> 6, lane = tid & 63;
  if (b < 24) {
    int m = b / 3, d = b % 3;
    const float* src = Vs + (size_t)(m*3 + d) * Nv;
    float s = 0.f;
    for (int n = tid; n < Nv; n += 256) s += src[n];
    s = wave_red_sum(s);
    if (lane == 0) sred[wave] = s;
    __syncthreads();
    if (tid == 0) {
      float tot = sred[0]+sred[1]+sred[2]+sred[3];
      ws[WS_T + m*3 + d] = -tot / (float)Nv;
    }
    if (d == 0 && tid < 9) {
      ws[WS_R + m*9 + tid] = (tid==0||tid==4||tid==8) ? 1.f : 0.f;
    }
  } else {
    float s = (tid < Kv) ? Q0[tid] : 0.f;
    s = wave_red_sum(s);
    if (lane == 0) sred[wave] = s;
    __syncthreads();
    if (tid == 0) {
      float mq = (sred[0]+sred[1]+sred[2]+sred[3]) / (float)Kv;
      ws[WS_BETA] = GAMMA_C * mq * sqrtf(mq);
    }
    if (tid < Kv) ws[WS_Q + tid] = Q0[tid];
    for (int i = tid; i < Kv*3; i += 256) ws[WS_X + i] = X0[i];
    for (int i = tid; i < ACCSZ; i += 256) ws[WS_ACC + i] = 0.f;
  }
}

// ---- fp32 Jacobi rotation, COMPILE-TIME pair, named scalars only.
#define JROTF(app,aqq,apq,apr,aqr, vp0,vp1,vp2, vq0,vq1,vq2) do {           \
    float tau_ = (aqq - app) * __builtin_amdgcn_rcpf(2.0f*apq);             \
    float tt_ = __builtin_amdgcn_rcpf(fabsf(tau_) +                         \
                   __builtin_amdgcn_sqrtf(fmaf(tau_,tau_,1.0f)));           \
    tt_ = (tau_ < 0.0f) ? -tt_ : tt_;                                       \
    tt_ = (apq == 0.0f) ? 0.0f : tt_;                                       \
    float c_ = __builtin_amdgcn_rsqf(fmaf(tt_,tt_,1.0f)), s_ = tt_*c_;      \
    float papq_ = apq;                                                      \
    app = fmaf(-tt_,papq_,app); aqq = fmaf(tt_,papq_,aqq); apq = 0.0f;      \
    float tp_ = apr, tq_ = aqr;                                             \
    apr = c_*tp_ - s_*tq_; aqr = s_*tp_ + c_*tq_;                           \
    tp_=vp0; tq_=vq0; vp0=c_*tp_-s_*tq_; vq0=s_*tp_+c_*tq_;                 \
    tp_=vp1; tq_=vq1; vp1=c_*tp_-s_*tq_; vq1=s_*tp_+c_*tq_;                 \
    tp_=vp2; tq_=vq2; vp2=c_*tp_-s_*tq_; vq2=s_*tp_+c_*tq_;                 \
  } while(0)

#define CSWAP3F(la,lb, a0,a1,a2, b0,b1,b2) do {                             \
    if (la < lb) { float t_;                                                \
      t_=la; la=lb; lb=t_; t_=a0; a0=b0; b0=t_;                             \
      t_=a1; a1=b1; b1=t_; t_=a2; a2=b2; b2=t_; }                           \
  } while(0)

// ---- redundant small update for iteration `itprev` from acc -> sX/sQ/sR/sT.
// Runs identically in every block. Contains one internal __syncthreads;
// caller must __syncthreads() after before reading other threads' sX/sQ.
template<int ITPREV>
__device__ __forceinline__ void small_update(const float* __restrict__ acc,
                                             const float* __restrict__ ws,
                                             int tid,
                                             float (*sX)[3], float* sQ,
                                             float (*sR)[9], float (*sT)[3],
                                             float* sTn) {
  const int k = tid;
  float lk[Mv], w0v[Mv], w1v[Mv], w2v[Mv], hk[Mv];
  #pragma unroll
  for (int mm=0;mm<Mv;mm++) {
    lk[mm]  = acc[AC_L + mm*Kv + k];
    w0v[mm] = acc[AC_W + (mm*3+0)*Kv + k];
    w1v[mm] = acc[AC_W + (mm*3+1)*Kv + k];
    w2v[mm] = acc[AC_W + (mm*3+2)*Kv + k];
    hk[mm]  = acc[AC_H + mm*Kv + k];
  }
  float xp0 = 0.f, xp1 = 0.f, xp2 = 0.f;
  if (ITPREV <= 1) {
    xp0 = ws[WS_X + k*3+0]; xp1 = ws[WS_X + k*3+1]; xp2 = ws[WS_X + k*3+2];
  }

  if (tid < Mv) {
    int mm = tid;
    const float* st = acc + AC_STATS + mm*16;
    float s0=st[0], s1=st[1], s2v=st[2], s3=st[3], s4=st[4], s5=st[5],
          s6=st[6], s7=st[7], s8=st[8], s9=st[9], s10=st[10], s11=st[11],
          s12=st[12], s13=st[13], s14=st[14], s15=st[15];
    float z = s0;
    float mX0 = s1, mX1 = s2v, mX2 = s3;
    float mW0 = s4, mW1 = s5, mW2 = s6;
    float iz = __builtin_amdgcn_rcpf(z);
    float P00 = s7  - mX0*mW0*iz;
    float P01 = s8  - mX0*mW1*iz;
    float P02 = s9  - mX0*mW2*iz;
    float P10 = s10 - mX1*mW0*iz;
    float P11 = s11 - mX1*mW1*iz;
    float P12 = s12 - mX1*mW2*iz;
    float P20 = s13 - mX2*mW0*iz;
    float P21 = s14 - mX2*mW1*iz;
    float P22 = s15 - mX2*mW2*iz;
    float a00 = P00*P00 + P10*P10 + P20*P20;
    float a01 = P00*P01 + P10*P11 + P20*P21;
    float a02 = P00*P02 + P10*P12 + P20*P22;
    float a11 = P01*P01 + P11*P11 + P21*P21;
    float a12 = P01*P02 + P11*P12 + P21*P22;
    float a22 = P02*P02 + P12*P12 + P22*P22;
    float v00=1, v01=0, v02=0, v10=0, v11=1, v12=0, v20=0, v21=0, v22=1;
    #pragma unroll 1
    for (int sweep = 0; sweep < 8; sweep++) {
      JROTF(a00,a11,a01, a02,a12, v00,v10,v20, v01,v11,v21);
      JROTF(a00,a22,a02, a01,a12, v00,v10,v20, v02,v12,v22);
      JROTF(a11,a22,a12, a01,a02, v01,v11,v21, v02,v12,v22);
    }
    float l0 = a00, l1 = a11, l2 = a22;
    CSWAP3F(l0,l1, v00,v10,v20, v01,v11,v21);
    CSWAP3F(l1,l2, v01,v11,v21, v02,v12,v22);
    CSWAP3F(l0,l1, v00,v10,v20, v01,v11,v21);
    float detP = P00*(P11*P22-P12*P21) - P01*(P10*P22-P12*P20)
               + P02*(P10*P21-P11*P20);
    float s2d = (detP < 0.0f) ? -1.0f : 1.0f;
    float tiny = 1e-18f*l0 + 1e-30f;
    float w0i = __builtin_amdgcn_rsqf(fmaxf(l0,tiny));
    float w1i = __builtin_amdgcn_rsqf(fmaxf(l1,tiny));
    float w2i = s2d*__builtin_amdgcn_rsqf(fmaxf(l2,tiny));
    float M00 = w0i*v00*v00 + w1i*v01*v01 + w2i*v02*v02;
    float M01 = w0i*v00*v10 + w1i*v01*v11 + w2i*v02*v12;
    float M02 = w0i*v00*v20 + w1i*v01*v21 + w2i*v02*v22;
    float M11 = w0i*v10*v10 + w1i*v11*v11 + w2i*v12*v12;
    float M12 = w0i*v10*v20 + w1i*v11*v21 + w2i*v12*v22;
    float M22 = w0i*v20*v20 + w1i*v21*v21 + w2i*v22*v22;
    float R00n = P00*M00 + P01*M01 + P02*M02;
    float R01n = P00*M01 + P01*M11 + P02*M12;
    float R02n = P00*M02 + P01*M12 + P02*M22;
    float R10n = P10*M00 + P11*M01 + P12*M02;
    float R11n = P10*M01 + P11*M11 + P12*M12;
    float R12n = P10*M02 + P11*M12 + P12*M22;
    float R20n = P20*M00 + P21*M01 + P22*M02;
    float R21n = P20*M01 + P21*M11 + P22*M12;
    float R22n = P20*M02 + P21*M12 + P22*M22;
    float tm0 = (mX0 - (R00n*mW0 + R01n*mW1 + R02n*mW2))*iz;
    float tm1 = (mX1 - (R10n*mW0 + R11n*mW1 + R12n*mW2))*iz;
    float tm2 = (mX2 - (R20n*mW0 + R21n*mW1 + R22n*mW2))*iz;
    sR[mm][0]=R00n; sR[mm][1]=R01n; sR[mm][2]=R02n;
    sR[mm][3]=R10n; sR[mm][4]=R11n; sR[mm][5]=R12n;
    sR[mm][6]=R20n; sR[mm][7]=R21n; sR[mm][8]=R22n;
    sT[mm][0]=tm0; sT[mm][1]=tm1; sT[mm][2]=tm2;
    sTn[mm] = tm0*tm0 + tm1*tm1 + tm2*tm2;
  }
  __syncthreads();
  {
    float den = 0.f, Xn0=0.f, Xn1=0.f, Xn2=0.f, S2=0.f;
    #pragma unroll
    for (int mm=0;mm<Mv;mm++) {
      float r0 = sR[mm][0]*w0v[mm] + sR[mm][1]*w1v[mm] + sR[mm][2]*w2v[mm];
      float r1 = sR[mm][3]*w0v[mm] + sR[mm][4]*w1v[mm] + sR[mm][5]*w2v[mm];
      float r2 = sR[mm][6]*w0v[mm] + sR[mm][7]*w1v[mm] + sR[mm][8]*w2v[mm];
      float tt0 = sT[mm][0], tt1 = sT[mm][1], tt2 = sT[mm][2];
      den += lk[mm];
      Xn0 += r0 + tt0*lk[mm]; Xn1 += r1 + tt1*lk[mm]; Xn2 += r2 + tt2*lk[mm];
      S2  += hk[mm] + 2.f*(tt0*r0+tt1*r1+tt2*r2) + sTn[mm]*lk[mm];
    }
    float x0, x1, x2;
    if (ITPREV > 1) { float inv = __builtin_amdgcn_rcpf(den);
                      x0=Xn0*inv; x1=Xn1*inv; x2=Xn2*inv; }
    else            { x0=xp0; x1=xp1; x2=xp2; }
    float wn = S2 + (x0*x0+x1*x1+x2*x2)*den - 2.f*(x0*Xn0+x1*Xn1+x2*Xn2);
    float qn = 3.f*den / (wn + 3.f*den*EPSILON_C);
    sX[k][0]=x0; sX[k][1]=x1; sX[k][2]=x2;
    sQ[k] = qn;
  }
}

// ------------------------------------------- one-iteration kernel (256 blocks)
// Two-pass, zero cross-lane ops in the main loops:
//   pass 1 (lane=n): per-thread point, per-thread softmax denominator.
//   pass 2 (lane=k): per-thread cluster, per-thread L/W/H accumulators.
template<int IT>
__global__ __launch_bounds__(256) void p_iter(const float* __restrict__ Vs,
                                              float* __restrict__ ws) {
  __shared__ __align__(16) float sC[Kv][8];    // kXx,kXy,kXz,kA,kB,kQ32,-,-  (8 KB)
  __shared__ __align__(16) float sPT[NPB][4];  // px,py,pz,tvn                (4 KB)
  __shared__ __align__(16) float sVV[NPB][4];  // vx,vy,vz,vn                 (4 KB)
  __shared__ float sInv[NPB];                  // 1/(sum+beta)                (1 KB)
  __shared__ float st4[4][16];
  __shared__ float sX[Kv][3];
  __shared__ float sQ[Kv];
  __shared__ float sR[Mv][9];
  __shared__ float sT[Mv][3];
  __shared__ float sTn[Mv];

  int tid  = threadIdx.x;
  int wave = tid >> 6, lane = tid & 63;
  int bid  = blockIdx.x;
  int m    = bid / BPM;
  int blk  = bid % BPM;
  int n0   = blk * NPB;

  float* acc  = ws + WS_ACC + (IT % 3)*ACCSZ;
  float* accz = ws + WS_ACC + ((IT+1) % 3)*ACCSZ;
  float beta = ws[WS_BETA];

  if (IT == 0) {
    if (tid < 72) ((float*)sR)[tid] = ws[WS_R + tid];
    if (tid < 24) ((float*)sT)[tid] = ws[WS_T + tid];
    sX[tid][0] = ws[WS_X + 3*tid+0];
    sX[tid][1] = ws[WS_X + 3*tid+1];
    sX[tid][2] = ws[WS_X + 3*tid+2];
    sQ[tid]    = ws[WS_Q + tid];
  } else {
    const float* accp = ws + WS_ACC + ((IT+2) % 3)*ACCSZ;  // (IT-1)%3
    small_update<(IT > 0) ? (IT-1) : 0>(accp, ws, tid, sX, sQ, sR, sT, sTn);
  }
  __syncthreads();

  // partitioned zero of buffer (IT+1)%3 (41*256 >= ACCSZ)
  { int base = bid*41;
    if (tid < 41 && base + tid < ACCSZ) accz[base + tid] = 0.f; }

  // ---- prep: per-k coefficients (k = tid), kept in regs AND staged to LDS
  const float L2E = 1.4426950408889634f;   // log2(e) folded into exp coeffs
  float xx = sX[tid][0], xy = sX[tid][1], xz = sX[tid][2];
  float q  = sQ[tid];
  float qL   = q * L2E;
  float kA   = -0.5f*qL;
  float kXx  = qL*xx, kXy = qL*xy, kXz = qL*xz;
  float kB   = kA*(xx*xx+xy*xy+xz*xz);
  float kQ32 = q*sqrtf(q);
  sC[tid][0]=kXx; sC[tid][1]=kXy; sC[tid][2]=kXz;
  sC[tid][3]=kA;  sC[tid][4]=kB;  sC[tid][5]=kQ32;

  // ---- per-thread point load + transform (n = n0 + tid, coalesced)
  float R00=sR[m][0],R01=sR[m][1],R02=sR[m][2];
  float R10=sR[m][3],R11=sR[m][4],R12=sR[m][5];
  float R20=sR[m][6],R21=sR[m][7],R22=sR[m][8];
  float t0=sT[m][0], t1=sT[m][1], t2=sT[m][2];
  int n = n0 + tid;
  float vx = Vs[(size_t)(m*3+0)*Nv + n];
  float vy = Vs[(size_t)(m*3+1)*Nv + n];
  float vz = Vs[(size_t)(m*3+2)*Nv + n];
  float px = fmaf(R00,vx, fmaf(R01,vy, fmaf(R02,vz, t0)));
  float py = fmaf(R10,vx, fmaf(R11,vy, fmaf(R12,vz, t1)));
  float pz = fmaf(R20,vx, fmaf(R21,vy, fmaf(R22,vz, t2)));
  float tvn = fmaf(px,px, fmaf(py,py, pz*pz));
  float vn  = fmaf(vx,vx, fmaf(vy,vy, vz*vz));
  sPT[tid][0]=px; sPT[tid][1]=py; sPT[tid][2]=pz; sPT[tid][3]=tvn;
  sVV[tid][0]=vx; sVV[tid][1]=vy; sVV[tid][2]=vz; sVV[tid][3]=vn;
  __syncthreads();

  // ---- pass 1: softmax denominator for OWN point, thread-local (no x-lane)
  {
    float s0=0.f, s1=0.f, s2=0.f, s3=0.f;
    #pragma unroll 2
    for (int k = 0; k < Kv; k += 4) {
      float4 c0 = *reinterpret_cast<const float4*>(&sC[k+0][0]);
      float2 d0 = *reinterpret_cast<const float2*>(&sC[k+0][4]);
      float4 c1 = *reinterpret_cast<const float4*>(&sC[k+1][0]);
      float2 d1 = *reinterpret_cast<const float2*>(&sC[k+1][4]);
      float4 c2 = *reinterpret_cast<const float4*>(&sC[k+2][0]);
      float2 d2 = *reinterpret_cast<const float2*>(&sC[k+2][4]);
      float4 c3 = *reinterpret_cast<const float4*>(&sC[k+3][0]);
      float2 d3 = *reinterpret_cast<const float2*>(&sC[k+3][4]);
      float a0 = fmaf(px,c0.x, fmaf(py,c0.y, fmaf(pz,c0.z, fmaf(c0.w,tvn,d0.x))));
      float a1 = fmaf(px,c1.x, fmaf(py,c1.y, fmaf(pz,c1.z, fmaf(c1.w,tvn,d1.x))));
      float a2 = fmaf(px,c2.x, fmaf(py,c2.y, fmaf(pz,c2.z, fmaf(c2.w,tvn,d2.x))));
      float a3 = fmaf(px,c3.x, fmaf(py,c3.y, fmaf(pz,c3.z, fmaf(c3.w,tvn,d3.x))));
      s0 = fmaf(__builtin_amdgcn_exp2f(a0), d0.y, s0);
      s1 = fmaf(__builtin_amdgcn_exp2f(a1), d1.y, s1);
      s2 = fmaf(__builtin_amdgcn_exp2f(a2), d2.y, s2);
      s3 = fmaf(__builtin_amdgcn_exp2f(a3), d3.y, s3);
    }
    sInv[tid] = __builtin_amdgcn_rcpf(((s0+s1)+(s2+s3)) + beta);
  }
  __syncthreads();

  // ---- pass 2: accumulate L/W/H for OWN cluster k=tid, thread-local
  float aL=0.f, aWx=0.f, aWy=0.f, aWz=0.f, aH=0.f;
  #pragma unroll 4
  for (int nn = 0; nn < NPB; nn++) {
    float4 p = *reinterpret_cast<const float4*>(&sPT[nn][0]);
    float4 v = *reinterpret_cast<const float4*>(&sVV[nn][0]);
    float iv = sInv[nn];
    float arg = fmaf(kXx,p.x, fmaf(kXy,p.y, fmaf(kXz,p.z, fmaf(kA,p.w,kB))));
    float a = __builtin_amdgcn_exp2f(arg) * (kQ32*iv);
    aL += a;
    aWx = fmaf(a,v.x,aWx);
    aWy = fmaf(a,v.y,aWy);
    aWz = fmaf(a,v.z,aWz);
    aH  = fmaf(a,v.w,aH);
  }
  atomicAdd(&acc[AC_L + m*Kv + tid], aL);
  atomicAdd(&acc[AC_W + (m*3+0)*Kv + tid], aWx);
  atomicAdd(&acc[AC_W + (m*3+1)*Kv + tid], aWy);
  atomicAdd(&acc[AC_W + (m*3+2)*Kv + tid], aWz);
  atomicAdd(&acc[AC_H + m*Kv + tid], aH);

  // ---- stats epilogue (block-level 16-way reduction, as before)
  {
    float bk = aL*q;
    float sw0 = aWx*q, sw1 = aWy*q, sw2 = aWz*q;
    float pr[16];
    pr[0]=bk;  pr[1]=bk*xx; pr[2]=bk*xy; pr[3]=bk*xz;
    pr[4]=sw0; pr[5]=sw1;   pr[6]=sw2;
    pr[7]=sw0*xx;  pr[8]=sw1*xx;  pr[9]=sw2*xx;
    pr[10]=sw0*xy; pr[11]=sw1*xy; pr[12]=sw2*xy;
    pr[13]=sw0*xz; pr[14]=sw1*xz; pr[15]=sw2*xz;
    float red[16];
    #pragma unroll
    for (int v2=0; v2<16; v2++) red[v2] = wave_red_sum(pr[v2]);
    if (lane == 0) {
      #pragma unroll
      for (int v2=0; v2<16; v2++) st4[wave][v2] = red[v2];
    }
    __syncthreads();
    if (tid < 16)
      atomicAdd(&acc[AC_STATS + m*16 + ((tid + blk) & 15)],
                st4[0][(tid+blk)&15]+st4[1][(tid+blk)&15]+
                st4[2][(tid+blk)&15]+st4[3][(tid+blk)&15]);
  }
}

// ------------------------------- final: prologue finalizes iter 5, then write
#define OUT_TOTAL (Mv*3*Nv + 72 + 24 + Kv*3)
__global__ __launch_bounds__(256) void p3_final(const float* __restrict__ Vs,
                                                const float* __restrict__ ws,
                                                float* __restrict__ out) {
  __shared__ float sX[Kv][3];
  __shared__ float sQ[Kv];
  __shared__ float sR[Mv][9];
  __shared__ float sT[Mv][3];
  __shared__ float sTn[Mv];
  int tid = threadIdx.x;
  const float* acc = ws + WS_ACC + ((NITER-1) % 3)*ACCSZ;
  small_update<NITER-1>(acc, ws, tid, sX, sQ, sR, sT, sTn);
  __syncthreads();

  for (int idx = blockIdx.x*256 + tid; idx < OUT_TOTAL; idx += 256*256) {
    if (idx < Mv*3*Nv) {
      int m = idx / (3*Nv);
      int r = idx % (3*Nv);
      int d = r / Nv;
      int n = r % Nv;
      float vx = Vs[(size_t)(m*3+0)*Nv + n];
      float vy = Vs[(size_t)(m*3+1)*Nv + n];
      float vz = Vs[(size_t)(m*3+2)*Nv + n];
      out[idx] = fmaf(sR[m][d*3+0],vx,
                 fmaf(sR[m][d*3+1],vy,
                 fmaf(sR[m][d*3+2],vz, sT[m][d])));
    } else {
      int j = idx - Mv*3*Nv;
      float v;
      if (j < 72)      v = ((float*)sR)[j];
      else if (j < 96) v = ((float*)sT)[j-72];
      else             v = ((float*)sX)[j-96];
      out[idx] = v;
    }
  }
}

extern "C" void kernel_launch(void* const* d_in, const int* in_sizes, int n_in,
                              void* d_out, int out_size, void* d_ws, size_t ws_size,
                              hipStream_t stream) {
  const float* Vs = (const float*)d_in[0];
  const float* X0 = (const float*)d_in[1];
  const float* Q0 = (const float*)d_in[2];
  float* out = (float*)d_out;
  float* ws  = (float*)d_ws;

  p0_init<<<25, 256, 0, stream>>>(Vs, X0, Q0, ws);
  p_iter<0><<<NBLK, 256, 0, stream>>>(Vs, ws);
  p_iter<1><<<NBLK, 256, 0, stream>>>(Vs, ws);
  p_iter<2><<<NBLK, 256, 0, stream>>>(Vs, ws);
  p_iter<3><<<NBLK, 256, 0, stream>>>(Vs, ws);
  p_iter<4><<<NBLK, 256, 0, stream>>>(Vs, ws);
  p_iter<5><<<NBLK, 256, 0, stream>>>(Vs, ws);
  p3_final<<<256, 256, 0, stream>>>(Vs, ws, out);
}

// Round 3
// 183.556 us; speedup vs baseline: 1.2327x; 1.1315x over previous
//
#include <hip/hip_runtime.h>
#include <math.h>

#define Mv 8
#define Nv 8192
#define Kv 256
#define BPM 64            // slabs per m -> 512 blocks total, 2 per CU
#define NBLK (Mv*BPM)
#define NPB (Nv/BPM)      // 128 points per block
#define NITER 6
#define EPSILON_C 0.01f
#define GAMMA_C 0.005f

// LDS row swizzles: 4 distinct rows read per wave land in distinct banks
#define SWZK(k) ((((k)&63)<<2)|((k)>>6))   // k = ks*64+j  -> row (j<<2)|ks
#define SWZP(p) ((((p)&31)<<2)|((p)>>5))   // p = ns*32+j  -> row (j<<2)|ns

// ws layout (float offsets)
#define WS_R     0        // 72   (M x 3 x 3) -- initial identity (p0)
#define WS_T     72       // 24   (M x 3)     -- initial t0 (p0)
#define WS_X     96       // 768  (K x 3)     -- X0 (p0; never overwritten)
#define WS_Q     864      // 256  -- Q0
#define WS_BETA  1120     // 1
#define WS_ACC   1124     // 3 x ACCSZ triple-buffered accumulators
#define AC_STATS 0        // 128 (M x 16)
#define AC_L     128      // 2048 (M x K)
#define AC_W     2176     // 6144 (M x 3 x K)
#define AC_H     8320     // 2048 (M x K)
#define ACCSZ    10368

// ---- wave-wide sum via DPP; wave-uniform result. All lanes must be active.
__device__ __forceinline__ float wave_red_sum(float x) {
  int v;
  float t;
  v = __builtin_bit_cast(int, x);
  t = __builtin_bit_cast(float, __builtin_amdgcn_update_dpp(0, v, 0x111, 0xf, 0xf, true));  // row_shr:1
  x += t; v = __builtin_bit_cast(int, x);
  t = __builtin_bit_cast(float, __builtin_amdgcn_update_dpp(0, v, 0x112, 0xf, 0xf, true));  // row_shr:2
  x += t; v = __builtin_bit_cast(int, x);
  t = __builtin_bit_cast(float, __builtin_amdgcn_update_dpp(0, v, 0x114, 0xf, 0xf, true));  // row_shr:4
  x += t; v = __builtin_bit_cast(int, x);
  t = __builtin_bit_cast(float, __builtin_amdgcn_update_dpp(0, v, 0x118, 0xf, 0xf, true));  // row_shr:8
  x += t; v = __builtin_bit_cast(int, x);
  t = __builtin_bit_cast(float, __builtin_amdgcn_update_dpp(0, v, 0x142, 0xa, 0xf, false)); // row_bcast:15
  x += t; v = __builtin_bit_cast(int, x);
  t = __builtin_bit_cast(float, __builtin_amdgcn_update_dpp(0, v, 0x143, 0xc, 0xf, false)); // row_bcast:31
  x += t;
  return __builtin_bit_cast(float, __builtin_amdgcn_readlane(__builtin_bit_cast(int, x), 63));
}

// ---- sum across a quad of lanes (xor1 + xor2 via quad_perm DPP). All lanes get it.
__device__ __forceinline__ float quad_red_sum(float x) {
  int v = __builtin_bit_cast(int, x);
  float t = __builtin_bit_cast(float, __builtin_amdgcn_update_dpp(0, v, 0xB1, 0xf, 0xf, true)); // quad_perm[1,0,3,2]
  x += t; v = __builtin_bit_cast(int, x);
  t = __builtin_bit_cast(float, __builtin_amdgcn_update_dpp(0, v, 0x4E, 0xf, 0xf, true));       // quad_perm[2,3,0,1]
  x += t;
  return x;
}

__device__ __forceinline__ float sel4(int c, float a0, float a1, float a2, float a3) {
  float r = a0;
  r = (c==1) ? a1 : r;
  r = (c==2) ? a2 : r;
  r = (c==3) ? a3 : r;
  return r;
}

// ---------------------------------------------------------------- init
__global__ __launch_bounds__(256) void p0_init(const float* __restrict__ Vs,
                                               const float* __restrict__ X0,
                                               const float* __restrict__ Q0,
                                               float* __restrict__ ws) {
  __shared__ float sred[4];
  int tid = threadIdx.x;
  int b = blockIdx.x;
  int wave = tid >> 6, lane = tid & 63;
  if (b < 24) {
    int m = b / 3, d = b % 3;
    const float* src = Vs + (size_t)(m*3 + d) * Nv;
    float s = 0.f;
    for (int n = tid; n < Nv; n += 256) s += src[n];
    s = wave_red_sum(s);
    if (lane == 0) sred[wave] = s;
    __syncthreads();
    if (tid == 0) {
      float tot = sred[0]+sred[1]+sred[2]+sred[3];
      ws[WS_T + m*3 + d] = -tot / (float)Nv;
    }
    if (d == 0 && tid < 9) {
      ws[WS_R + m*9 + tid] = (tid==0||tid==4||tid==8) ? 1.f : 0.f;
    }
  } else {
    float s = (tid < Kv) ? Q0[tid] : 0.f;
    s = wave_red_sum(s);
    if (lane == 0) sred[wave] = s;
    __syncthreads();
    if (tid == 0) {
      float mq = (sred[0]+sred[1]+sred[2]+sred[3]) / (float)Kv;
      ws[WS_BETA] = GAMMA_C * mq * sqrtf(mq);
    }
    if (tid < Kv) ws[WS_Q + tid] = Q0[tid];
    for (int i = tid; i < Kv*3; i += 256) ws[WS_X + i] = X0[i];
    for (int i = tid; i < ACCSZ; i += 256) ws[WS_ACC + i] = 0.f;
  }
}

// ---- fp32 Jacobi rotation, COMPILE-TIME pair, named scalars only.
#define JROTF(app,aqq,apq,apr,aqr, vp0,vp1,vp2, vq0,vq1,vq2) do {           \
    float tau_ = (aqq - app) * __builtin_amdgcn_rcpf(2.0f*apq);             \
    float tt_ = __builtin_amdgcn_rcpf(fabsf(tau_) +                         \
                   __builtin_amdgcn_sqrtf(fmaf(tau_,tau_,1.0f)));           \
    tt_ = (tau_ < 0.0f) ? -tt_ : tt_;                                       \
    tt_ = (apq == 0.0f) ? 0.0f : tt_;                                       \
    float c_ = __builtin_amdgcn_rsqf(fmaf(tt_,tt_,1.0f)), s_ = tt_*c_;      \
    float papq_ = apq;                                                      \
    app = fmaf(-tt_,papq_,app); aqq = fmaf(tt_,papq_,aqq); apq = 0.0f;      \
    float tp_ = apr, tq_ = aqr;                                             \
    apr = c_*tp_ - s_*tq_; aqr = s_*tp_ + c_*tq_;                           \
    tp_=vp0; tq_=vq0; vp0=c_*tp_-s_*tq_; vq0=s_*tp_+c_*tq_;                 \
    tp_=vp1; tq_=vq1; vp1=c_*tp_-s_*tq_; vq1=s_*tp_+c_*tq_;                 \
    tp_=vp2; tq_=vq2; vp2=c_*tp_-s_*tq_; vq2=s_*tp_+c_*tq_;                 \
  } while(0)

#define CSWAP3F(la,lb, a0,a1,a2, b0,b1,b2) do {                             \
    if (la < lb) { float t_;                                                \
      t_=la; la=lb; lb=t_; t_=a0; a0=b0; b0=t_;                             \
      t_=a1; a1=b1; b1=t_; t_=a2; a2=b2; b2=t_; }                           \
  } while(0)

// ---- redundant small update for iteration `itprev` from acc -> sX/sQ/sR/sT.
template<int ITPREV>
__device__ __forceinline__ void small_update(const float* __restrict__ acc,
                                             const float* __restrict__ ws,
                                             int tid,
                                             float (*sX)[3], float* sQ,
                                             float (*sR)[9], float (*sT)[3],
                                             float* sTn) {
  const int k = tid;
  float lk[Mv], w0v[Mv], w1v[Mv], w2v[Mv], hk[Mv];
  #pragma unroll
  for (int mm=0;mm<Mv;mm++) {
    lk[mm]  = acc[AC_L + mm*Kv + k];
    w0v[mm] = acc[AC_W + (mm*3+0)*Kv + k];
    w1v[mm] = acc[AC_W + (mm*3+1)*Kv + k];
    w2v[mm] = acc[AC_W + (mm*3+2)*Kv + k];
    hk[mm]  = acc[AC_H + mm*Kv + k];
  }
  float xp0 = 0.f, xp1 = 0.f, xp2 = 0.f;
  if (ITPREV <= 1) {
    xp0 = ws[WS_X + k*3+0]; xp1 = ws[WS_X + k*3+1]; xp2 = ws[WS_X + k*3+2];
  }

  if (tid < Mv) {
    int mm = tid;
    const float* st = acc + AC_STATS + mm*16;
    float s0=st[0], s1=st[1], s2v=st[2], s3=st[3], s4=st[4], s5=st[5],
          s6=st[6], s7=st[7], s8=st[8], s9=st[9], s10=st[10], s11=st[11],
          s12=st[12], s13=st[13], s14=st[14], s15=st[15];
    float z = s0;
    float mX0 = s1, mX1 = s2v, mX2 = s3;
    float mW0 = s4, mW1 = s5, mW2 = s6;
    float iz = __builtin_amdgcn_rcpf(z);
    float P00 = s7  - mX0*mW0*iz;
    float P01 = s8  - mX0*mW1*iz;
    float P02 = s9  - mX0*mW2*iz;
    float P10 = s10 - mX1*mW0*iz;
    float P11 = s11 - mX1*mW1*iz;
    float P12 = s12 - mX1*mW2*iz;
    float P20 = s13 - mX2*mW0*iz;
    float P21 = s14 - mX2*mW1*iz;
    float P22 = s15 - mX2*mW2*iz;
    float a00 = P00*P00 + P10*P10 + P20*P20;
    float a01 = P00*P01 + P10*P11 + P20*P21;
    float a02 = P00*P02 + P10*P12 + P20*P22;
    float a11 = P01*P01 + P11*P11 + P21*P21;
    float a12 = P01*P02 + P11*P12 + P21*P22;
    float a22 = P02*P02 + P12*P12 + P22*P22;
    float v00=1, v01=0, v02=0, v10=0, v11=1, v12=0, v20=0, v21=0, v22=1;
    #pragma unroll 1
    for (int sweep = 0; sweep < 8; sweep++) {
      JROTF(a00,a11,a01, a02,a12, v00,v10,v20, v01,v11,v21);
      JROTF(a00,a22,a02, a01,a12, v00,v10,v20, v02,v12,v22);
      JROTF(a11,a22,a12, a01,a02, v01,v11,v21, v02,v12,v22);
    }
    float l0 = a00, l1 = a11, l2 = a22;
    CSWAP3F(l0,l1, v00,v10,v20, v01,v11,v21);
    CSWAP3F(l1,l2, v01,v11,v21, v02,v12,v22);
    CSWAP3F(l0,l1, v00,v10,v20, v01,v11,v21);
    float detP = P00*(P11*P22-P12*P21) - P01*(P10*P22-P12*P20)
               + P02*(P10*P21-P11*P20);
    float s2d = (detP < 0.0f) ? -1.0f : 1.0f;
    float tiny = 1e-18f*l0 + 1e-30f;
    float w0i = __builtin_amdgcn_rsqf(fmaxf(l0,tiny));
    float w1i = __builtin_amdgcn_rsqf(fmaxf(l1,tiny));
    float w2i = s2d*__builtin_amdgcn_rsqf(fmaxf(l2,tiny));
    float M00 = w0i*v00*v00 + w1i*v01*v01 + w2i*v02*v02;
    float M01 = w0i*v00*v10 + w1i*v01*v11 + w2i*v02*v12;
    float M02 = w0i*v00*v20 + w1i*v01*v21 + w2i*v02*v22;
    float M11 = w0i*v10*v10 + w1i*v11*v11 + w2i*v12*v12;
    float M12 = w0i*v10*v20 + w1i*v11*v21 + w2i*v12*v22;
    float M22 = w0i*v20*v20 + w1i*v21*v21 + w2i*v22*v22;
    float R00n = P00*M00 + P01*M01 + P02*M02;
    float R01n = P00*M01 + P01*M11 + P02*M12;
    float R02n = P00*M02 + P01*M12 + P02*M22;
    float R10n = P10*M00 + P11*M01 + P12*M02;
    float R11n = P10*M01 + P11*M11 + P12*M12;
    float R12n = P10*M02 + P11*M12 + P12*M22;
    float R20n = P20*M00 + P21*M01 + P22*M02;
    float R21n = P20*M01 + P21*M11 + P22*M12;
    float R22n = P20*M02 + P21*M12 + P22*M22;
    float tm0 = (mX0 - (R00n*mW0 + R01n*mW1 + R02n*mW2))*iz;
    float tm1 = (mX1 - (R10n*mW0 + R11n*mW1 + R12n*mW2))*iz;
    float tm2 = (mX2 - (R20n*mW0 + R21n*mW1 + R22n*mW2))*iz;
    sR[mm][0]=R00n; sR[mm][1]=R01n; sR[mm][2]=R02n;
    sR[mm][3]=R10n; sR[mm][4]=R11n; sR[mm][5]=R12n;
    sR[mm][6]=R20n; sR[mm][7]=R21n; sR[mm][8]=R22n;
    sT[mm][0]=tm0; sT[mm][1]=tm1; sT[mm][2]=tm2;
    sTn[mm] = tm0*tm0 + tm1*tm1 + tm2*tm2;
  }
  __syncthreads();
  {
    float den = 0.f, Xn0=0.f, Xn1=0.f, Xn2=0.f, S2=0.f;
    #pragma unroll
    for (int mm=0;mm<Mv;mm++) {
      float r0 = sR[mm][0]*w0v[mm] + sR[mm][1]*w1v[mm] + sR[mm][2]*w2v[mm];
      float r1 = sR[mm][3]*w0v[mm] + sR[mm][4]*w1v[mm] + sR[mm][5]*w2v[mm];
      float r2 = sR[mm][6]*w0v[mm] + sR[mm][7]*w1v[mm] + sR[mm][8]*w2v[mm];
      float tt0 = sT[mm][0], tt1 = sT[mm][1], tt2 = sT[mm][2];
      den += lk[mm];
      Xn0 += r0 + tt0*lk[mm]; Xn1 += r1 + tt1*lk[mm]; Xn2 += r2 + tt2*lk[mm];
      S2  += hk[mm] + 2.f*(tt0*r0+tt1*r1+tt2*r2) + sTn[mm]*lk[mm];
    }
    float x0, x1, x2;
    if (ITPREV > 1) { float inv = __builtin_amdgcn_rcpf(den);
                      x0=Xn0*inv; x1=Xn1*inv; x2=Xn2*inv; }
    else            { x0=xp0; x1=xp1; x2=xp2; }
    float wn = S2 + (x0*x0+x1*x1+x2*x2)*den - 2.f*(x0*Xn0+x1*Xn1+x2*Xn2);
    float qn = 3.f*den / (wn + 3.f*den*EPSILON_C);
    sX[k][0]=x0; sX[k][1]=x1; sX[k][2]=x2;
    sQ[k] = qn;
  }
}

// ------------------------------------------- one-iteration kernel (512 blocks)
// Register-tiled two-pass:
//  pass 1: thread = (point-pair pg, k-quarter ks=tid&3). Each sC read serves
//          2 (k,n) pairs; quad_perm DPP reduces the 4 k-quarters. Stores
//          li = -log2(S+beta) so the normalizer folds into pass-2's exponent.
//  pass 2: thread = (k-quad kg, n-quarter ns=tid&3). 4 k coefficient sets in
//          registers; each point read serves 4 pairs; quad_perm reduces the
//          4 n-quarters; thread t atomics k = t.
template<int IT>
__global__ __launch_bounds__(256) void p_iter(const float* __restrict__ Vs,
                                              float* __restrict__ ws) {
  __shared__ __align__(16) float sC4[Kv][4];   // {kXx,kXy,kXz,kA} swizzled (4 KB)
  __shared__ float sKC[Kv];                    // kQ32*2^kB swizzled (1 KB)
  __shared__ __align__(16) float sP4[NPB][4];  // {px,py,pz,tvn} swizzled (2 KB)
  __shared__ __align__(16) float sV4[NPB][4];  // {vx,vy,vz,vn} swizzled (2 KB)
  __shared__ float sLi[NPB];                   // -log2(S+beta) swizzled (0.5 KB)
  __shared__ float st4[4][16];
  __shared__ float sX[Kv][3];
  __shared__ float sQ[Kv];
  __shared__ float sR[Mv][9];
  __shared__ float sT[Mv][3];
  __shared__ float sTn[Mv];

  int tid  = threadIdx.x;
  int wave = tid >> 6, lane = tid & 63;
  int bid  = blockIdx.x;
  int m    = bid / BPM;
  int blk  = bid % BPM;
  int n0   = blk * NPB;

  float* acc  = ws + WS_ACC + (IT % 3)*ACCSZ;
  float* accz = ws + WS_ACC + ((IT+1) % 3)*ACCSZ;
  float beta = ws[WS_BETA];

  if (IT == 0) {
    if (tid < 72) ((float*)sR)[tid] = ws[WS_R + tid];
    if (tid < 24) ((float*)sT)[tid] = ws[WS_T + tid];
    sX[tid][0] = ws[WS_X + 3*tid+0];
    sX[tid][1] = ws[WS_X + 3*tid+1];
    sX[tid][2] = ws[WS_X + 3*tid+2];
    sQ[tid]    = ws[WS_Q + tid];
  } else {
    const float* accp = ws + WS_ACC + ((IT+2) % 3)*ACCSZ;  // (IT-1)%3
    small_update<(IT > 0) ? (IT-1) : 0>(accp, ws, tid, sX, sQ, sR, sT, sTn);
  }
  __syncthreads();

  // partitioned zero of buffer (IT+1)%3 (21*512 >= ACCSZ)
  { int base = bid*21;
    if (tid < 21 && base + tid < ACCSZ) accz[base + tid] = 0.f; }

  // ---- prep: per-k coefficients (k=tid) -> swizzled LDS; points -> LDS
  const float L2E = 1.4426950408889634f;
  {
    float xx = sX[tid][0], xy = sX[tid][1], xz = sX[tid][2];
    float q  = sQ[tid];
    float qL = q * L2E;
    float kA = -0.5f*qL;
    float kB = kA*(xx*xx+xy*xy+xz*xz);
    float kQ32 = q*sqrtf(q);
    int rr = SWZK(tid);
    *reinterpret_cast<float4*>(&sC4[rr][0]) = make_float4(qL*xx, qL*xy, qL*xz, kA);
    sKC[rr] = kQ32 * __builtin_amdgcn_exp2f(kB);
  }
  if (tid < NPB) {
    float R00=sR[m][0],R01=sR[m][1],R02=sR[m][2];
    float R10=sR[m][3],R11=sR[m][4],R12=sR[m][5];
    float R20=sR[m][6],R21=sR[m][7],R22=sR[m][8];
    float t0=sT[m][0], t1=sT[m][1], t2=sT[m][2];
    int n = n0 + tid;
    float vx = Vs[(size_t)(m*3+0)*Nv + n];
    float vy = Vs[(size_t)(m*3+1)*Nv + n];
    float vz = Vs[(size_t)(m*3+2)*Nv + n];
    float px = fmaf(R00,vx, fmaf(R01,vy, fmaf(R02,vz, t0)));
    float py = fmaf(R10,vx, fmaf(R11,vy, fmaf(R12,vz, t1)));
    float pz = fmaf(R20,vx, fmaf(R21,vy, fmaf(R22,vz, t2)));
    float tvn = fmaf(px,px, fmaf(py,py, pz*pz));
    float vn  = fmaf(vx,vx, fmaf(vy,vy, vz*vz));
    int pr = SWZP(tid);
    *reinterpret_cast<float4*>(&sP4[pr][0]) = make_float4(px,py,pz,tvn);
    *reinterpret_cast<float4*>(&sV4[pr][0]) = make_float4(vx,vy,vz,vn);
  }
  __syncthreads();

  // ---- pass 1: denominators. thread (pg = tid>>2, ks = tid&3)
  {
    int ks = tid & 3, pg = tid >> 2;          // pg in 0..63, points 2pg, 2pg+1
    float4 P0 = *reinterpret_cast<const float4*>(&sP4[SWZP(2*pg+0)][0]);
    float4 P1 = *reinterpret_cast<const float4*>(&sP4[SWZP(2*pg+1)][0]);
    float s0 = 0.f, s1 = 0.f;
    #pragma unroll 4
    for (int j = 0; j < Kv/4; j++) {          // k = ks*64 + j
      int row = (j<<2) | ks;
      float4 c4 = *reinterpret_cast<const float4*>(&sC4[row][0]);
      float kc = sKC[row];
      float a0 = fmaf(P0.x,c4.x, fmaf(P0.y,c4.y, fmaf(P0.z,c4.z, P0.w*c4.w)));
      float a1 = fmaf(P1.x,c4.x, fmaf(P1.y,c4.y, fmaf(P1.z,c4.z, P1.w*c4.w)));
      s0 = fmaf(__builtin_amdgcn_exp2f(a0), kc, s0);
      s1 = fmaf(__builtin_amdgcn_exp2f(a1), kc, s1);
    }
    float S0 = quad_red_sum(s0);
    float S1 = quad_red_sum(s1);
    if (ks < 2) {
      float Ssel = (ks == 1) ? S1 : S0;
      sLi[SWZP(2*pg + ks)] = -__log2f(Ssel + beta);
    }
  }
  __syncthreads();

  // ---- pass 2: thread (kg = tid>>2, ns = tid&3); owns k = 4kg..4kg+3
  float cXx0,cXy0,cXz0,cA0,cC0, cXx1,cXy1,cXz1,cA1,cC1,
        cXx2,cXy2,cXz2,cA2,cC2, cXx3,cXy3,cXz3,cA3,cC3;
  {
    int kg = tid >> 2;
    #define LDC(c) { int rr = SWZK(4*kg + c); \
      float4 t4 = *reinterpret_cast<const float4*>(&sC4[rr][0]); \
      cXx##c=t4.x; cXy##c=t4.y; cXz##c=t4.z; cA##c=t4.w; cC##c=sKC[rr]; }
    LDC(0) LDC(1) LDC(2) LDC(3)
    #undef LDC
  }
  float L0=0,L1=0,L2=0,L3=0, Wx0=0,Wx1=0,Wx2=0,Wx3=0,
        Wy0=0,Wy1=0,Wy2=0,Wy3=0, Wz0=0,Wz1=0,Wz2=0,Wz3=0,
        H0=0,H1=0,H2=0,H3=0;
  {
    int ns = tid & 3;
    #pragma unroll 4
    for (int j = 0; j < NPB/4; j++) {         // n = ns*32 + j
      int prow = (j<<2) | ns;
      float4 p4 = *reinterpret_cast<const float4*>(&sP4[prow][0]);
      float4 v4 = *reinterpret_cast<const float4*>(&sV4[prow][0]);
      float li = sLi[prow];
      #define P2K(c) { \
        float arg = fmaf(p4.w, cA##c, li); \
        arg = fmaf(p4.x, cXx##c, fmaf(p4.y, cXy##c, fmaf(p4.z, cXz##c, arg))); \
        float e = __builtin_amdgcn_exp2f(arg) * cC##c; \
        L##c += e; \
        Wx##c = fmaf(e, v4.x, Wx##c); Wy##c = fmaf(e, v4.y, Wy##c); \
        Wz##c = fmaf(e, v4.z, Wz##c); H##c  = fmaf(e, v4.w, H##c); }
      P2K(0) P2K(1) P2K(2) P2K(3)
      #undef P2K
    }
  }
  // quad-reduce the 4 n-quarters; then thread t owns k = t
  L0=quad_red_sum(L0); L1=quad_red_sum(L1); L2=quad_red_sum(L2); L3=quad_red_sum(L3);
  Wx0=quad_red_sum(Wx0); Wx1=quad_red_sum(Wx1); Wx2=quad_red_sum(Wx2); Wx3=quad_red_sum(Wx3);
  Wy0=quad_red_sum(Wy0); Wy1=quad_red_sum(Wy1); Wy2=quad_red_sum(Wy2); Wy3=quad_red_sum(Wy3);
  Wz0=quad_red_sum(Wz0); Wz1=quad_red_sum(Wz1); Wz2=quad_red_sum(Wz2); Wz3=quad_red_sum(Wz3);
  H0=quad_red_sum(H0); H1=quad_red_sum(H1); H2=quad_red_sum(H2); H3=quad_red_sum(H3);
  int c = tid & 3;
  float vL  = sel4(c, L0,L1,L2,L3);
  float vWx = sel4(c, Wx0,Wx1,Wx2,Wx3);
  float vWy = sel4(c, Wy0,Wy1,Wy2,Wy3);
  float vWz = sel4(c, Wz0,Wz1,Wz2,Wz3);
  float vH  = sel4(c, H0,H1,H2,H3);
  atomicAdd(&acc[AC_L + m*Kv + tid], vL);
  atomicAdd(&acc[AC_W + (m*3+0)*Kv + tid], vWx);
  atomicAdd(&acc[AC_W + (m*3+1)*Kv + tid], vWy);
  atomicAdd(&acc[AC_W + (m*3+2)*Kv + tid], vWz);
  atomicAdd(&acc[AC_H + m*Kv + tid], vH);

  // ---- stats epilogue (k = tid), same contract as before
  {
    float q  = sQ[tid];
    float x0 = sX[tid][0], x1 = sX[tid][1], x2 = sX[tid][2];
    float bk = vL*q;
    float sw0 = vWx*q, sw1 = vWy*q, sw2 = vWz*q;
    float pr[16];
    pr[0]=bk;  pr[1]=bk*x0; pr[2]=bk*x1; pr[3]=bk*x2;
    pr[4]=sw0; pr[5]=sw1;   pr[6]=sw2;
    pr[7]=sw0*x0;  pr[8]=sw1*x0;  pr[9]=sw2*x0;
    pr[10]=sw0*x1; pr[11]=sw1*x1; pr[12]=sw2*x1;
    pr[13]=sw0*x2; pr[14]=sw1*x2; pr[15]=sw2*x2;
    float red[16];
    #pragma unroll
    for (int v2=0; v2<16; v2++) red[v2] = wave_red_sum(pr[v2]);
    if (lane == 0) {
      #pragma unroll
      for (int v2=0; v2<16; v2++) st4[wave][v2] = red[v2];
    }
    __syncthreads();
    if (tid < 16)
      atomicAdd(&acc[AC_STATS + m*16 + ((tid + blk) & 15)],
                st4[0][(tid+blk)&15]+st4[1][(tid+blk)&15]+
                st4[2][(tid+blk)&15]+st4[3][(tid+blk)&15]);
  }
}

// ------------------------------- final: prologue finalizes iter 5, then write
#define OUT_TOTAL (Mv*3*Nv + 72 + 24 + Kv*3)
__global__ __launch_bounds__(256) void p3_final(const float* __restrict__ Vs,
                                                const float* __restrict__ ws,
                                                float* __restrict__ out) {
  __shared__ float sX[Kv][3];
  __shared__ float sQ[Kv];
  __shared__ float sR[Mv][9];
  __shared__ float sT[Mv][3];
  __shared__ float sTn[Mv];
  int tid = threadIdx.x;
  const float* acc = ws + WS_ACC + ((NITER-1) % 3)*ACCSZ;
  small_update<NITER-1>(acc, ws, tid, sX, sQ, sR, sT, sTn);
  __syncthreads();

  for (int idx = blockIdx.x*256 + tid; idx < OUT_TOTAL; idx += 256*256) {
    if (idx < Mv*3*Nv) {
      int m = idx / (3*Nv);
      int r = idx % (3*Nv);
      int d = r / Nv;
      int n = r % Nv;
      float vx = Vs[(size_t)(m*3+0)*Nv + n];
      float vy = Vs[(size_t)(m*3+1)*Nv + n];
      float vz = Vs[(size_t)(m*3+2)*Nv + n];
      out[idx] = fmaf(sR[m][d*3+0],vx,
                 fmaf(sR[m][d*3+1],vy,
                 fmaf(sR[m][d*3+2],vz, sT[m][d])));
    } else {
      int j = idx - Mv*3*Nv;
      float v;
      if (j < 72)      v = ((float*)sR)[j];
      else if (j < 96) v = ((float*)sT)[j-72];
      else             v = ((float*)sX)[j-96];
      out[idx] = v;
    }
  }
}

extern "C" void kernel_launch(void* const* d_in, const int* in_sizes, int n_in,
                              void* d_out, int out_size, void* d_ws, size_t ws_size,
                              hipStream_t stream) {
  const float* Vs = (const float*)d_in[0];
  const float* X0 = (const float*)d_in[1];
  const float* Q0 = (const float*)d_in[2];
  float* out = (float*)d_out;
  float* ws  = (float*)d_ws;

  p0_init<<<25, 256, 0, stream>>>(Vs, X0, Q0, ws);
  p_iter<0><<<NBLK, 256, 0, stream>>>(Vs, ws);
  p_iter<1><<<NBLK, 256, 0, stream>>>(Vs, ws);
  p_iter<2><<<NBLK, 256, 0, stream>>>(Vs, ws);
  p_iter<3><<<NBLK, 256, 0, stream>>>(Vs, ws);
  p_iter<4><<<NBLK, 256, 0, stream>>>(Vs, ws);
  p_iter<5><<<NBLK, 256, 0, stream>>>(Vs, ws);
  p3_final<<<256, 256, 0, stream>>>(Vs, ws, out);
}